// Round 1
// baseline (543.858 us; speedup 1.0000x reference)
//
#include <hip/hip_runtime.h>
#include <hip/hip_bf16.h>

typedef _Float16 h16;
typedef _Float16 h16x8 __attribute__((ext_vector_type(8)));
typedef float f32x4 __attribute__((ext_vector_type(4)));

#define DEVI static __device__ __forceinline__

constexpr int NN = 2048;     // sequence length
constexpr int DIM = 512;
constexpr int NH = 8;
constexpr int DH = 64;
constexpr int BH = 16;       // B * H
constexpr float FSCALE = 0.125f;  // DH^-0.5

DEVI f32x4 mfma16(h16x8 a, h16x8 b, f32x4 c) {
  return __builtin_amdgcn_mfma_f32_16x16x32_f16(a, b, c, 0, 0, 0);
}

DEVI void glds16(const void* g, void* l) {
  __builtin_amdgcn_global_load_lds(
      (const __attribute__((address_space(1))) unsigned int*)g,
      (__attribute__((address_space(3))) unsigned int*)l, 16, 0, 0);
}

DEVI void tri_decode(int p, int& a, int& b) {
  a = (int)((sqrtf(8.f * p + 1.f) - 1.f) * 0.5f);
  while ((a + 1) * (a + 2) / 2 <= p) ++a;
  while (a * (a + 1) / 2 > p) --a;
  b = p - a * (a + 1) / 2;
}

// ---------------- pack kernels ----------------

__global__ __launch_bounds__(256) void k_pack_x(const float* __restrict__ x, h16* __restrict__ xh) {
  int i = (blockIdx.x * 256 + threadIdx.x) * 4;
  float4 v = *(const float4*)(x + i);
  union { h16 h[4]; uint2 u; } pk;
  pk.h[0] = (h16)v.x; pk.h[1] = (h16)v.y; pk.h[2] = (h16)v.z; pk.h[3] = (h16)v.w;
  *(uint2*)(xh + i) = pk.u;
}

struct WPtrs { const float* w[7]; };

// transpose+cast each 512x512 weight: wt[o][k] = W[k][o]
__global__ __launch_bounds__(256) void k_pack_w(WPtrs wp, h16* __restrict__ wt) {
  const float* W = wp.w[blockIdx.z];
  h16* out = wt + (size_t)blockIdx.z * DIM * DIM;
  __shared__ h16 t[64][65];
  int k0 = blockIdx.x * 64, o0 = blockIdx.y * 64;
  int c = threadIdx.x & 63, r4 = threadIdx.x >> 6;
#pragma unroll
  for (int rr = 0; rr < 64; rr += 4) {
    int r = rr + r4;
    t[r][c] = (h16)W[(size_t)(k0 + r) * DIM + o0 + c];
  }
  __syncthreads();
#pragma unroll
  for (int rr = 0; rr < 64; rr += 4) {
    int r = rr + r4;
    out[(size_t)(o0 + r) * DIM + k0 + c] = t[c][r];
  }
}

// ---------------- projections ----------------
// qkv layout: [widx][bh][n][DH], widx: 0=Qu*s 1=Ku 2=Vu 3=Qc*s 4=Kc 5=Vc
__global__ __launch_bounds__(256) void k_proj(const h16* __restrict__ xh, const h16* __restrict__ wt,
                                              h16* __restrict__ qkv, h16* __restrict__ vcT) {
  int widx = blockIdx.z;
  const h16* W = wt + (size_t)widx * DIM * DIM;  // [o][k]
  int m0 = blockIdx.x * 64, o0 = blockIdx.y * 64;
  int lane = threadIdx.x & 63, wv = threadIdx.x >> 6;
  int kb = 8 * (lane >> 4);
  f32x4 acc[4] = {};
  const h16* ap = xh + (size_t)(m0 + 16 * wv + (lane & 15)) * DIM + kb;
  const h16* bp = W + (size_t)(o0 + (lane & 15)) * DIM + kb;
  for (int k0 = 0; k0 < DIM; k0 += 32) {
    h16x8 af = *(const h16x8*)(ap + k0);
#pragma unroll
    for (int t = 0; t < 4; t++) {
      h16x8 bfv = *(const h16x8*)(bp + (size_t)(16 * t) * DIM + k0);
      acc[t] = mfma16(af, bfv, acc[t]);
    }
  }
  float scl = (widx == 0 || widx == 3) ? FSCALE : 1.0f;
  int ri = m0 + 16 * wv + (lane >> 4) * 4;
  int c0 = o0 + (lane & 15);
#pragma unroll
  for (int t = 0; t < 4; t++) {
#pragma unroll
    for (int r = 0; r < 4; r++) {
      int gi = ri + r, go = c0 + 16 * t;
      float v = acc[t][r] * scl;
      int b = gi >> 11, n = gi & 2047, h = go >> 6, d = go & 63;
      qkv[(((size_t)widx * BH + b * NH + h) * NN + n) * DH + d] = (h16)v;
      if (widx == 5) vcT[((size_t)(b * NH + h) * DH + d) * NN + n] = (h16)v;
    }
  }
}

// ---------------- term1 & sigmoid matrices ----------------
// term[i][j] = (Qc_s[i]. Vu[j]) * [j<=i]      (SCALE folded into Qc_s)
// sig [k][j] = sigmoid(Qu_s[k] . Ku[j]) * [j>k]
__global__ __launch_bounds__(256) void k_termsig(const h16* __restrict__ qkv,
                                                 h16* __restrict__ term, h16* __restrict__ sig, int bh0) {
  int pidx = blockIdx.x;
  bool is_sig = blockIdx.y != 0;
  int lz = blockIdx.z, bh = bh0 + lz;
  int a, bq;
  tri_decode(pidx, a, bq);
  int rt = is_sig ? bq : a;  // row tile (k for sig, i for term)
  int jt = is_sig ? a : bq;  // col tile (j): term j<=i, sig j>=k
  const h16* A  = qkv + ((size_t)(is_sig ? 0 : 3) * BH + bh) * NN * DH;
  const h16* Bv = qkv + ((size_t)(is_sig ? 1 : 2) * BH + bh) * NN * DH;
  h16* out = (is_sig ? sig : term) + (size_t)lz * NN * NN;
  int lane = threadIdx.x & 63, wv = threadIdx.x >> 6;
  int wy = wv >> 1, wx = wv & 1;
  int r0 = rt * 128 + 64 * wy, c0 = jt * 128 + 64 * wx;
  int kb = 8 * (lane >> 4);
  f32x4 acc[4][4] = {};
  const h16* ap = A + (size_t)(r0 + (lane & 15)) * DH + kb;
  const h16* bp = Bv + (size_t)(c0 + (lane & 15)) * DH + kb;
#pragma unroll
  for (int ks = 0; ks < 2; ks++) {
    h16x8 af[4], bfv[4];
#pragma unroll
    for (int i = 0; i < 4; i++) af[i] = *(const h16x8*)(ap + (size_t)(16 * i) * DH + 32 * ks);
#pragma unroll
    for (int j = 0; j < 4; j++) bfv[j] = *(const h16x8*)(bp + (size_t)(16 * j) * DH + 32 * ks);
#pragma unroll
    for (int i = 0; i < 4; i++)
#pragma unroll
      for (int j = 0; j < 4; j++) acc[i][j] = mfma16(af[i], bfv[j], acc[i][j]);
  }
  int ri = r0 + (lane >> 4) * 4;
  int cj0 = c0 + (lane & 15);
#pragma unroll
  for (int i = 0; i < 4; i++)
#pragma unroll
    for (int j = 0; j < 4; j++)
#pragma unroll
      for (int r = 0; r < 4; r++) {
        int gr = ri + 16 * i + r;
        int gj = cj0 + 16 * j;
        float v = acc[i][j][r];
        float o;
        if (!is_sig) o = (gj <= gr) ? v : 0.f;
        else         o = (gj > gr) ? 1.f / (1.f + __expf(-v)) : 0.f;
        out[(size_t)gr * NN + gj] = (h16)o;
      }
}

// ---------------- big triangular GEMM: scores = Qc_s.Kc^T - silu(term @ sig^T), causal mask ----------------
__global__ __launch_bounds__(256) void k_scores(const h16* __restrict__ qkv,
                                                const h16* __restrict__ term, const h16* __restrict__ sig,
                                                h16* __restrict__ scores, int bh0) {
  int pidx = blockIdx.x, lz = blockIdx.z, bh = bh0 + lz;
  int It, Kt;
  tri_decode(pidx, It, Kt);  // It >= Kt
  __shared__ h16 Alds[128 * 64];
  __shared__ h16 Blds[128 * 64];
  int lane = threadIdx.x & 63, wv = threadIdx.x >> 6;
  int wy = wv >> 1, wx = wv & 1;
  const h16* Ab = term + (size_t)lz * NN * NN;
  const h16* Bb = sig + (size_t)lz * NN * NN;
  int i0 = It * 128, k0 = Kt * 128;
  f32x4 acc[4][4] = {};
  int srow = 32 * wv;
  int lr = lane >> 3, lc = 8 * (lane & 7);
  for (int js = k0; js < i0 + 128; js += 64) {
#pragma unroll
    for (int inst = 0; inst < 4; inst++) {
      int r = srow + 8 * inst;
      glds16(Ab + (size_t)(i0 + r + lr) * NN + js + lc, Alds + r * 64);
      glds16(Bb + (size_t)(k0 + r + lr) * NN + js + lc, Blds + r * 64);
    }
    __syncthreads();
#pragma unroll
    for (int ks = 0; ks < 2; ks++) {
      h16x8 af[4], bfv[4];
      int co = 32 * ks + 8 * (lane >> 4);
#pragma unroll
      for (int i = 0; i < 4; i++) af[i] = *(const h16x8*)(Alds + (64 * wy + 16 * i + (lane & 15)) * 64 + co);
#pragma unroll
      for (int j = 0; j < 4; j++) bfv[j] = *(const h16x8*)(Blds + (64 * wx + 16 * j + (lane & 15)) * 64 + co);
#pragma unroll
      for (int i = 0; i < 4; i++)
#pragma unroll
        for (int j = 0; j < 4; j++) acc[i][j] = mfma16(af[i], bfv[j], acc[i][j]);
    }
    __syncthreads();
  }
  // acc = -silu(S_u)
#pragma unroll
  for (int i = 0; i < 4; i++)
#pragma unroll
    for (int j = 0; j < 4; j++)
#pragma unroll
      for (int r = 0; r < 4; r++) {
        float xv = acc[i][j][r];
        acc[i][j][r] = -xv / (1.f + __expf(-xv));
      }
  // acc += Qc_s . Kc^T   (SCALE folded into Qc_s)
  const h16* Q  = qkv + ((size_t)3 * BH + bh) * NN * DH;
  const h16* Kc = qkv + ((size_t)4 * BH + bh) * NN * DH;
  int kb = 8 * (lane >> 4);
#pragma unroll
  for (int d2 = 0; d2 < 2; d2++) {
    h16x8 af[4], bfv[4];
#pragma unroll
    for (int i = 0; i < 4; i++)
      af[i] = *(const h16x8*)(Q + (size_t)(i0 + 64 * wy + 16 * i + (lane & 15)) * DH + 32 * d2 + kb);
#pragma unroll
    for (int j = 0; j < 4; j++)
      bfv[j] = *(const h16x8*)(Kc + (size_t)(k0 + 64 * wx + 16 * j + (lane & 15)) * DH + 32 * d2 + kb);
#pragma unroll
    for (int i = 0; i < 4; i++)
#pragma unroll
      for (int j = 0; j < 4; j++) acc[i][j] = mfma16(af[i], bfv[j], acc[i][j]);
  }
  h16* sc = scores + (size_t)lz * NN * NN;
  int ri = i0 + 64 * wy + (lane >> 4) * 4;
  int ck0 = k0 + 64 * wx + (lane & 15);
#pragma unroll
  for (int i = 0; i < 4; i++)
#pragma unroll
    for (int j = 0; j < 4; j++)
#pragma unroll
      for (int r = 0; r < 4; r++) {
        int gi = ri + 16 * i + r;
        int gk = ck0 + 16 * j;
        float v = (gk <= gi) ? acc[i][j][r] : -__builtin_inff();
        sc[(size_t)gi * NN + gk] = (h16)v;
      }
}

// ---------------- row softmax (in place, fp16 scores -> fp16 probs) ----------------
__global__ __launch_bounds__(256) void k_softmax(h16* __restrict__ sbuf) {
  int lane = threadIdx.x & 63, wv = threadIdx.x >> 6;
  int i = blockIdx.x * 4 + wv;
  int lz = blockIdx.y;
  h16* srow = sbuf + ((size_t)lz * NN + i) * NN;
  int kend = ((i >> 7) + 1) << 7;  // 128-aligned end of written region
  float v[32];
  float m = -__builtin_inff();
#pragma unroll
  for (int it = 0; it < 4; it++) {
    int base = it * 512 + lane * 8;
    if (base < kend) {
      h16x8 raw = *(const h16x8*)(srow + base);
#pragma unroll
      for (int e = 0; e < 8; e++) {
        float xv = (float)raw[e];
        v[it * 8 + e] = xv;
        m = fmaxf(m, xv);
      }
    } else {
#pragma unroll
      for (int e = 0; e < 8; e++) v[it * 8 + e] = -__builtin_inff();
    }
  }
#pragma unroll
  for (int off = 32; off > 0; off >>= 1) m = fmaxf(m, __shfl_xor(m, off));
  float s = 0.f;
#pragma unroll
  for (int t = 0; t < 32; t++) {
    float e = __expf(v[t] - m);
    v[t] = e;
    s += e;
  }
#pragma unroll
  for (int off = 32; off > 0; off >>= 1) s += __shfl_xor(s, off);
  float inv = 1.f / s;
#pragma unroll
  for (int it = 0; it < 4; it++) {
    int base = it * 512 + lane * 8;
    if (base < kend) {
      h16x8 o;
#pragma unroll
      for (int e = 0; e < 8; e++) o[e] = (h16)(v[it * 8 + e] * inv);
      *(h16x8*)(srow + base) = o;
    }
  }
}

// ---------------- PV: attn_out = P @ Vc ----------------
__global__ __launch_bounds__(256) void k_pv(const h16* __restrict__ P, const h16* __restrict__ vcT,
                                            h16* __restrict__ attn, int bh0) {
  int It = blockIdx.x, lz = blockIdx.z, bh = bh0 + lz;
  int lane = threadIdx.x & 63, wv = threadIdx.x >> 6;
  int wy = wv >> 1, wx = wv & 1;
  const h16* Pb = P + (size_t)lz * NN * NN;
  const h16* VT = vcT + (size_t)bh * DH * NN;  // [d][n]
  int i0 = It * 128;
  int kend = i0 + 128;
  f32x4 acc[4][2] = {};
  int kb = 8 * (lane >> 4);
  for (int kk = 0; kk < kend; kk += 32) {
    h16x8 af[4], bfv[2];
#pragma unroll
    for (int a = 0; a < 4; a++)
      af[a] = *(const h16x8*)(Pb + (size_t)(i0 + 64 * wy + 16 * a + (lane & 15)) * NN + kk + kb);
#pragma unroll
    for (int c = 0; c < 2; c++)
      bfv[c] = *(const h16x8*)(VT + (size_t)(32 * wx + 16 * c + (lane & 15)) * NN + kk + kb);
#pragma unroll
    for (int a = 0; a < 4; a++)
#pragma unroll
      for (int c = 0; c < 2; c++) acc[a][c] = mfma16(af[a], bfv[c], acc[a][c]);
  }
  int hh = bh & 7, b = bh >> 3;
  int ri = i0 + 64 * wy + (lane >> 4) * 4;
  int cd0 = 32 * wx + (lane & 15);
#pragma unroll
  for (int a = 0; a < 4; a++)
#pragma unroll
    for (int c = 0; c < 2; c++)
#pragma unroll
      for (int r = 0; r < 4; r++) {
        int gi = ri + 16 * a + r, gd = cd0 + 16 * c;
        attn[((size_t)b * NN + gi) * DIM + hh * DH + gd] = (h16)acc[a][c][r];
      }
}

// ---------------- output projection (fp32 out) ----------------
__global__ __launch_bounds__(256) void k_outproj(const h16* __restrict__ attn, const h16* __restrict__ Wt,
                                                 float* __restrict__ out) {
  int m0 = blockIdx.x * 64, o0 = blockIdx.y * 64;
  int lane = threadIdx.x & 63, wv = threadIdx.x >> 6;
  int kb = 8 * (lane >> 4);
  f32x4 acc[4] = {};
  const h16* ap = attn + (size_t)(m0 + 16 * wv + (lane & 15)) * DIM + kb;
  const h16* bp = Wt + (size_t)(o0 + (lane & 15)) * DIM + kb;
  for (int k0 = 0; k0 < DIM; k0 += 32) {
    h16x8 af = *(const h16x8*)(ap + k0);
#pragma unroll
    for (int t = 0; t < 4; t++) {
      h16x8 bfv = *(const h16x8*)(bp + (size_t)(16 * t) * DIM + k0);
      acc[t] = mfma16(af, bfv, acc[t]);
    }
  }
  int ri = m0 + 16 * wv + (lane >> 4) * 4;
  int c0 = o0 + (lane & 15);
#pragma unroll
  for (int t = 0; t < 4; t++)
#pragma unroll
    for (int r = 0; r < 4; r++) out[(size_t)(ri + r) * DIM + c0 + 16 * t] = acc[t][r];
}

// ---------------- launch ----------------

extern "C" void kernel_launch(void* const* d_in, const int* in_sizes, int n_in,
                              void* d_out, int out_size, void* d_ws, size_t ws_size,
                              hipStream_t stream) {
  const float* x = (const float*)d_in[0];
  WPtrs wp;
  for (int i = 0; i < 7; i++) wp.w[i] = (const float*)d_in[1 + i];

  char* p = (char*)d_ws;
  auto alloc = [&](size_t bytes) {
    void* r = (void*)p;
    p += (bytes + 255) & ~(size_t)255;
    return r;
  };
  h16* xh   = (h16*)alloc((size_t)4096 * DIM * 2);            // 4 MB
  h16* wt   = (h16*)alloc((size_t)7 * DIM * DIM * 2);         // 3.5 MB
  h16* qkv  = (h16*)alloc((size_t)6 * BH * NN * DH * 2);      // 24 MB
  h16* vcT  = (h16*)alloc((size_t)BH * DH * NN * 2);          // 4 MB
  h16* attn = (h16*)alloc((size_t)4096 * DIM * 2);            // 4 MB
  size_t used = (size_t)(p - (char*)d_ws);
  size_t per_bh = (size_t)NN * NN * 2;                        // 8 MB
  size_t avail = ws_size > used ? ws_size - used : 0;
  int CH = 16;
  while (CH > 1 && (size_t)CH * per_bh * 3 > avail) CH >>= 1;
  h16* term   = (h16*)alloc((size_t)CH * per_bh);
  h16* sig    = (h16*)alloc((size_t)CH * per_bh);
  h16* scores = (h16*)alloc((size_t)CH * per_bh);

  k_pack_x<<<dim3(2048), dim3(256), 0, stream>>>(x, xh);
  k_pack_w<<<dim3(8, 8, 7), dim3(256), 0, stream>>>(wp, wt);
  k_proj<<<dim3(64, 8, 6), dim3(256), 0, stream>>>(xh, wt, qkv, vcT);

  for (int c0 = 0; c0 < BH; c0 += CH) {
    hipMemsetAsync(term, 0, (size_t)CH * per_bh * 2, stream);  // term + sig (contiguous)
    k_termsig<<<dim3(136, 2, CH), dim3(256), 0, stream>>>(qkv, term, sig, c0);
    k_scores<<<dim3(136, 1, CH), dim3(256), 0, stream>>>(qkv, term, sig, scores, c0);
    k_softmax<<<dim3(NN / 4, CH), dim3(256), 0, stream>>>(scores);
    k_pv<<<dim3(16, 1, CH), dim3(256), 0, stream>>>(scores, vcT, attn, c0);
  }

  k_outproj<<<dim3(64, 8), dim3(256), 0, stream>>>(attn, wt + (size_t)6 * DIM * DIM, (float*)d_out);
}